// Round 11
// baseline (416.885 us; speedup 1.0000x reference)
//
#include <hip/hip_runtime.h>
#include <math.h>

#define NN 50000
#define EE 1000000
#define BB 512

__device__ __forceinline__ float sigmoidf_(float x) { return 1.0f / (1.0f + __expf(-x)); }

typedef __attribute__((ext_vector_type(16))) float f32x16;

__device__ __forceinline__ int uloadi(const int* p) {
    return __builtin_amdgcn_readfirstlane(*p);
}

// Scalar-pipe attr loads: 16 floats (one edge) per s_load_dwordx16 into SGPRs.
// Wait is inside the asm (rule: never split issue/wait across compiler-visible
// code without a sched fence). lgkmcnt only tracks SMEM/DS here (no DS in loop).
__device__ __forceinline__ void sload_pair(const float* p, f32x16& r0, f32x16& r1) {
    asm volatile("s_load_dwordx16 %0, %2, 0x0\n\t"
                 "s_load_dwordx16 %1, %2, 0x40\n\t"
                 "s_waitcnt lgkmcnt(0)"
                 : "=&s"(r0), "=&s"(r1)
                 : "s"(p));
}
__device__ __forceinline__ void sload_one(const float* p, f32x16& r0) {
    asm volatile("s_load_dwordx16 %0, %1, 0x0\n\t"
                 "s_waitcnt lgkmcnt(0)"
                 : "=&s"(r0)
                 : "s"(p));
}

// ---------------------------------------------------------------------------
// CSR build, single atomic pass: rank -> scan -> pack (atomic-free).
// ---------------------------------------------------------------------------
__global__ __launch_bounds__(256) void rank_kernel(const int* __restrict__ ei,
                                                   int* __restrict__ counts,
                                                   int* __restrict__ rnk)
{
    int e = blockIdx.x * 256 + threadIdx.x;
    if (e < EE) rnk[e] = atomicAdd(&counts[ei[EE + e]], 1);
}

__global__ __launch_bounds__(1024) void scan_kernel(const int* __restrict__ counts,
                                                    int* __restrict__ rowptr)
{
    __shared__ int s[1024];
    int t = threadIdx.x;
    const int CH = (NN + 1023) / 1024;
    int lo = t * CH, hi = lo + CH < NN ? lo + CH : NN;
    int sum = 0;
    for (int i = lo; i < hi; ++i) sum += counts[i];
    s[t] = sum;
    __syncthreads();
    for (int off = 1; off < 1024; off <<= 1) {
        int v = (t >= off) ? s[t - off] : 0;
        __syncthreads();
        s[t] += v;
        __syncthreads();
    }
    int base = (t > 0) ? s[t - 1] : 0;
    for (int i = lo; i < hi; ++i) { rowptr[i] = base; base += counts[i]; }
    if (t == 1023) rowptr[NN] = s[1023];
}

__global__ __launch_bounds__(256) void pack_kernel(
    const int* __restrict__ ei, const int* __restrict__ rnk,
    const int* __restrict__ rowptr,
    const float* __restrict__ eattr, const float* __restrict__ efeat,
    int* __restrict__ srcp, float* __restrict__ ea16)
{
    int e = blockIdx.x * 256 + threadIdx.x;
    if (e >= EE) return;
    int pos = rowptr[ei[EE + e]] + rnk[e];
    srcp[pos] = ei[e];
    const float4* pa = reinterpret_cast<const float4*>(eattr) + (size_t)e * 2;
    const float4* pf = reinterpret_cast<const float4*>(efeat) + (size_t)e * 2;
    float4* o = reinterpret_cast<float4*>(ea16 + (size_t)pos * 16);
    o[0] = pa[0]; o[1] = pa[1]; o[2] = pf[0]; o[3] = pf[1];
}

__global__ __launch_bounds__(256) void pack_ids_kernel(
    const int* __restrict__ ei, const int* __restrict__ rnk,
    const int* __restrict__ rowptr, int* __restrict__ perm)
{
    int e = blockIdx.x * 256 + threadIdx.x;
    if (e < EE) perm[rowptr[ei[EE + e]] + rnk[e]] = e;
}

__global__ __launch_bounds__(256) void batch_bounds_kernel(const int* __restrict__ batch,
                                                           int* __restrict__ brow)
{
    int i = blockIdx.x * 256 + threadIdx.x;
    if (i >= NN) return;
    int bi = batch[i];
    int prev = (i == 0) ? -1 : batch[i - 1];
    for (int v = prev + 1; v <= bi; ++v) brow[v] = i;
    if (i == NN - 1) for (int v = bi + 1; v <= BB; ++v) brow[v] = NN;
}

__global__ __launch_bounds__(256) void transpose_w_kernel(const float* __restrict__ wih,
                                                          const float* __restrict__ whh,
                                                          float* __restrict__ wihT,
                                                          float* __restrict__ whhT)
{
    int i = blockIdx.x * 256 + threadIdx.x;
    if (i < 128 * 256) {
        int k = i >> 8, g = i & 255;
        wihT[i] = wih[g * 128 + k];
    } else if (i < 192 * 256) {
        int j = i - 128 * 256;
        int k = j >> 8, g = j & 255;
        whhT[j] = whh[g * 64 + k];
    }
}

// ---------------------------------------------------------------------------
// Fused GINE layer: scalar-pipe attr loads (s_load_dwordx16), 2-edge unroll.
// Per edge: ~16 v_fmac (SGPR x VGPR) + 1 coalesced 256B gather + 1 SMEM load.
// ---------------------------------------------------------------------------
template <int CIN, bool PACKED>
__global__ __launch_bounds__(256) void gine_fused_kernel(
    const float* __restrict__ xin, const int* __restrict__ ei,
    const int* __restrict__ pidx,   // PACKED ? srcp : perm
    const int* __restrict__ rowptr,
    const float* __restrict__ eattr, const float* __restrict__ efeat,
    const float* __restrict__ ea16,
    const float* __restrict__ ew, const float* __restrict__ eb,
    const float* __restrict__ w1, const float* __restrict__ b1,
    const float* __restrict__ w2, const float* __restrict__ b2,
    float* __restrict__ hout)
{
    __shared__ float w1_lds[CIN * 64];
    for (int i = threadIdx.x; i < CIN * 64; i += 256) w1_lds[i] = w1[i];
    __syncthreads();

    int wave = threadIdx.x >> 6, lane = threadIdx.x & 63;
    int node = blockIdx.x * 4 + wave;
    if (node >= NN) return;

    int ch = lane & (CIN - 1);

    float wreg[16];
#pragma unroll
    for (int k = 0; k < 16; ++k) wreg[k] = ew[k * CIN + ch];
    float ebv = eb[ch];

    int start = rowptr[node], end = rowptr[node + 1];
    float agg = 0.0f;

    if constexpr (PACKED) {
        if constexpr (CIN == 64) {
            int j = start;
            for (; j + 1 < end; j += 2) {
                int jb = __builtin_amdgcn_readfirstlane(j);
                int s0 = uloadi(pidx + jb);
                int s1 = uloadi(pidx + jb + 1);
                float m0 = xin[(size_t)s0 * 64 + lane] + ebv;   // gathers issue
                float m1 = xin[(size_t)s1 * 64 + lane] + ebv;
                f32x16 a0, a1;
                sload_pair(ea16 + (size_t)jb * 16, a0, a1);     // scalar pipe
#pragma unroll
                for (int k = 0; k < 16; ++k) {
                    m0 += a0[k] * wreg[k];
                    m1 += a1[k] * wreg[k];
                }
                agg += fmaxf(m0, 0.0f) + fmaxf(m1, 0.0f);
            }
            if (j < end) {
                int jb = __builtin_amdgcn_readfirstlane(j);
                int s0 = uloadi(pidx + jb);
                float m0 = xin[(size_t)s0 * 64 + lane] + ebv;
                f32x16 a0;
                sload_one(ea16 + (size_t)jb * 16, a0);
#pragma unroll
                for (int k = 0; k < 16; ++k) m0 += a0[k] * wreg[k];
                agg += fmaxf(m0, 0.0f);
            }
        } else {
            // CIN == 32: one edge per half-wave; both sums from SGPR operands.
            int half = lane >> 5;
            int j = start;
            for (; j + 1 < end; j += 2) {
                int jb = __builtin_amdgcn_readfirstlane(j);
                int s0 = uloadi(pidx + jb);
                int s1 = uloadi(pidx + jb + 1);
                float xv = xin[(size_t)(half ? s1 : s0) * 32 + ch];
                f32x16 a0, a1;
                sload_pair(ea16 + (size_t)jb * 16, a0, a1);
                float m0 = 0.0f, m1 = 0.0f;
#pragma unroll
                for (int k = 0; k < 16; ++k) {
                    m0 += a0[k] * wreg[k];
                    m1 += a1[k] * wreg[k];
                }
                float m = half ? m1 : m0;
                agg += fmaxf(xv + m + ebv, 0.0f);
            }
            if (j < end) {  // single tail edge: only half 0 contributes
                int jb = __builtin_amdgcn_readfirstlane(j);
                int s0 = uloadi(pidx + jb);
                float xv = xin[(size_t)s0 * 32 + ch];
                f32x16 a0;
                sload_one(ea16 + (size_t)jb * 16, a0);
                float m0 = 0.0f;
#pragma unroll
                for (int k = 0; k < 16; ++k) m0 += a0[k] * wreg[k];
                agg += (half == 0) ? fmaxf(xv + m0 + ebv, 0.0f) : 0.0f;
            }
            agg += __shfl_xor(agg, 32);
        }
    } else {
        // Fallback: perm indirection (no packed ea16). Scalar loads via asm on
        // the two 8-float halves of eattr/efeat.
        for (int j = start; j < end; ++j) {
            int jb = __builtin_amdgcn_readfirstlane(j);
            int e = uloadi(pidx + jb);
            int s0 = uloadi(ei + e);
            float xv = xin[(size_t)s0 * CIN + ch];
            f32x16 a0;
            {   // two dwordx8 halves as one dwordx16? sources differ; do 2 asm
                typedef __attribute__((ext_vector_type(8))) float f32x8;
                f32x8 lo, hi;
                asm volatile("s_load_dwordx8 %0, %1, 0x0\n\ts_waitcnt lgkmcnt(0)"
                             : "=&s"(lo) : "s"(eattr + (size_t)e * 8));
                asm volatile("s_load_dwordx8 %0, %1, 0x0\n\ts_waitcnt lgkmcnt(0)"
                             : "=&s"(hi) : "s"(efeat + (size_t)e * 8));
#pragma unroll
                for (int k = 0; k < 8; ++k) { a0[k] = lo[k]; a0[8 + k] = hi[k]; }
            }
            float m0 = xv + ebv;
#pragma unroll
            for (int k = 0; k < 16; ++k) m0 += a0[k] * wreg[k];
            if constexpr (CIN == 64) agg += fmaxf(m0, 0.0f);
            else                      agg += (lane < 32) ? fmaxf(m0, 0.0f) : 0.0f;
        }
        if constexpr (CIN == 32) agg += __shfl_xor(agg, 32);
    }

    float h_in = 0.0f;
    if (lane < CIN) h_in = xin[(size_t)node * CIN + lane] + agg;

    float hid = b1[lane];
#pragma unroll
    for (int i = 0; i < CIN; ++i)
        hid += __shfl(h_in, i) * w1_lds[i * 64 + lane];
    hid = fmaxf(hid, 0.0f);

    float o = b2[lane];
#pragma unroll
    for (int i = 0; i < 64; ++i)
        o += __shfl(hid, i) * w2[i * 64 + lane];

    hout[(size_t)node * 64 + lane] = fmaxf(o, 0.0f);
}

// ---------------------------------------------------------------------------
// Set2Set v3: single-sweep online softmax per wave, one cross-wave combine.
// ---------------------------------------------------------------------------
__global__ __launch_bounds__(1024) void set2set_head_v3(
    const float* __restrict__ h2, const int* __restrict__ brow,
    const float* __restrict__ wihT, const float* __restrict__ whhT,
    const float* __restrict__ bih, const float* __restrict__ bhh,
    const float* __restrict__ dw, const float* __restrict__ db,
    const float* __restrict__ ow, const float* __restrict__ ob,
    float* __restrict__ outp)
{
    int b = blockIdx.x, tid = threadIdx.x;
    int wv = tid >> 6, lane = tid & 63;
    __shared__ float qstar[128], hh[64], cc[64];
    __shared__ float gpart[4][256];
    __shared__ float redw[16][64];
    __shared__ float redm[16], reds[16];

    int start = brow[b], end = brow[b + 1];

    if (tid < 128) qstar[tid] = 0.0f;
    if (tid < 64) { hh[tid] = 0.0f; cc[tid] = 0.0f; }
    __syncthreads();

    for (int step = 0; step < 3; ++step) {
        {
            int p = tid >> 8, g = tid & 255;
            float acc = 0.0f;
            const float* wT = wihT + (size_t)(32 * p) * 256 + g;
#pragma unroll 8
            for (int k = 0; k < 32; ++k) acc += qstar[32 * p + k] * wT[(size_t)k * 256];
            const float* hT = whhT + (size_t)(16 * p) * 256 + g;
#pragma unroll 8
            for (int k = 0; k < 16; ++k) acc += hh[16 * p + k] * hT[(size_t)k * 256];
            gpart[p][g] = acc;
        }
        __syncthreads();
        if (tid < 64) {
            float gi = bih[tid]       + bhh[tid]       + gpart[0][tid]       + gpart[1][tid]       + gpart[2][tid]       + gpart[3][tid];
            float gf = bih[64 + tid]  + bhh[64 + tid]  + gpart[0][64 + tid]  + gpart[1][64 + tid]  + gpart[2][64 + tid]  + gpart[3][64 + tid];
            float gg = bih[128 + tid] + bhh[128 + tid] + gpart[0][128 + tid] + gpart[1][128 + tid] + gpart[2][128 + tid] + gpart[3][128 + tid];
            float go = bih[192 + tid] + bhh[192 + tid] + gpart[0][192 + tid] + gpart[1][192 + tid] + gpart[2][192 + tid] + gpart[3][192 + tid];
            float c = sigmoidf_(gf) * cc[tid] + sigmoidf_(gi) * tanhf(gg);
            cc[tid] = c;
            hh[tid] = sigmoidf_(go) * tanhf(c);
        }
        __syncthreads();

        float qv = hh[lane];
        float mw = -INFINITY, sw = 0.0f, rw = 0.0f;
        for (int n = start + wv; n < end; n += 16) {
            float v = h2[(size_t)n * 64 + lane];
            float p = v * qv;
#pragma unroll
            for (int off = 32; off; off >>= 1) p += __shfl_xor(p, off);
            float nm = fmaxf(mw, p);
            float sc = __expf(mw - nm);
            float pe = __expf(p - nm);
            sw = sw * sc + pe;
            rw = rw * sc + pe * v;
            mw = nm;
        }
        redm[wv] = mw; reds[wv] = sw; redw[wv][lane] = rw;
        __syncthreads();
        if (tid < 64) {
            float M = -INFINITY;
#pragma unroll
            for (int w = 0; w < 16; ++w) M = fmaxf(M, redm[w]);
            float S = 0.0f, R = 0.0f;
#pragma unroll
            for (int w = 0; w < 16; ++w) {
                float mm = redm[w];
                if (mm > -INFINITY) {
                    float sc = __expf(mm - M);
                    S += reds[w] * sc;
                    R += redw[w][tid] * sc;
                }
            }
            qstar[tid] = hh[tid];
            qstar[64 + tid] = (S > 0.0f) ? R / S : 0.0f;
        }
        __syncthreads();
    }

    if (tid < 64) {
        float z = db[tid];
#pragma unroll 4
        for (int k = 0; k < 128; ++k) z += qstar[k] * dw[k * 64 + tid];
        redw[0][tid] = fmaxf(z, 0.0f);
    }
    __syncthreads();
    if (tid < 64) {
        float t = redw[0][tid] * ow[tid];
#pragma unroll
        for (int off = 32; off; off >>= 1) t += __shfl_xor(t, off);
        if (tid == 0) outp[b] = t + ob[0];
    }
}

// ---------------------------------------------------------------------------
extern "C" void kernel_launch(void* const* d_in, const int* in_sizes, int n_in,
                              void* d_out, int out_size, void* d_ws, size_t ws_size,
                              hipStream_t stream)
{
    const float* x     = (const float*)d_in[0];
    const float* eattr = (const float*)d_in[1];
    const float* efeat = (const float*)d_in[2];
    const int*   ei    = (const int*)d_in[3];
    const int*   batch = (const int*)d_in[4];
    const float* c0_ew = (const float*)d_in[5];  const float* c0_eb = (const float*)d_in[6];
    const float* c0_w1 = (const float*)d_in[7];  const float* c0_b1 = (const float*)d_in[8];
    const float* c0_w2 = (const float*)d_in[9];  const float* c0_b2 = (const float*)d_in[10];
    const float* c1_ew = (const float*)d_in[11]; const float* c1_eb = (const float*)d_in[12];
    const float* c1_w1 = (const float*)d_in[13]; const float* c1_b1 = (const float*)d_in[14];
    const float* c1_w2 = (const float*)d_in[15]; const float* c1_b2 = (const float*)d_in[16];
    const float* wih   = (const float*)d_in[17]; const float* bih   = (const float*)d_in[18];
    const float* whh   = (const float*)d_in[19]; const float* bhh   = (const float*)d_in[20];
    const float* dw    = (const float*)d_in[21]; const float* dbias = (const float*)d_in[22];
    const float* ow    = (const float*)d_in[23]; const float* ob    = (const float*)d_in[24];

    float* out = (float*)d_out;
    int* iws = (int*)d_ws;

    // layout (4B words): counts NN | rowptr NN+1 | brow BB+1 | wihT 32768 |
    //                    whhT 16384 | srcp EE | [align64B] ea16 16EE | h1 | h2
    // rnk (EE words) aliases h1: pack reads it before gine32 writes h1.
    int* counts = iws;
    int* rowptr = counts + NN;
    int* brow   = rowptr + NN + 1;
    size_t off0 = ((size_t)2 * NN + 1 + (BB + 1) + 15) & ~(size_t)15;
    float* wihT = (float*)(iws + off0);
    float* whhT = wihT + 128 * 256;
    int*   srcp = (int*)(whhT + 64 * 256);
    size_t offE = (off0 + 128 * 256 + 64 * 256 + EE + 15) & ~(size_t)15;
    float* ea16 = (float*)(iws + offE);
    float* h1   = ea16 + (size_t)EE * 16;
    float* h2   = h1 + (size_t)NN * 64;
    int*   rnk  = (int*)h1;
    const size_t needP = (offE + (size_t)EE * 16 + (size_t)NN * 128) * sizeof(int);

    hipMemsetAsync(counts, 0, (size_t)NN * sizeof(int), stream);
    batch_bounds_kernel<<<(NN + 255) / 256, 256, 0, stream>>>(batch, brow);
    transpose_w_kernel<<<192, 256, 0, stream>>>(wih, whh, wihT, whhT);

    if (ws_size >= needP) {
        rank_kernel<<<(EE + 255) / 256, 256, 0, stream>>>(ei, counts, rnk);
        scan_kernel<<<1, 1024, 0, stream>>>(counts, rowptr);
        pack_kernel<<<(EE + 255) / 256, 256, 0, stream>>>(
            ei, rnk, rowptr, eattr, efeat, srcp, ea16);
        gine_fused_kernel<32, true><<<(NN + 3) / 4, 256, 0, stream>>>(
            x, ei, srcp, rowptr, eattr, efeat, ea16,
            c0_ew, c0_eb, c0_w1, c0_b1, c0_w2, c0_b2, h1);
        gine_fused_kernel<64, true><<<(NN + 3) / 4, 256, 0, stream>>>(
            h1, ei, srcp, rowptr, eattr, efeat, ea16,
            c1_ew, c1_eb, c1_w1, c1_b1, c1_w2, c1_b2, h2);
    } else {
        int* perm = srcp;
        float* h1f = (float*)(iws + offE);
        float* h2f = h1f + (size_t)NN * 64;
        int* rnkf  = (int*)(h2f + (size_t)NN * 64);
        rank_kernel<<<(EE + 255) / 256, 256, 0, stream>>>(ei, counts, rnkf);
        scan_kernel<<<1, 1024, 0, stream>>>(counts, rowptr);
        pack_ids_kernel<<<(EE + 255) / 256, 256, 0, stream>>>(ei, rnkf, rowptr, perm);
        gine_fused_kernel<32, false><<<(NN + 3) / 4, 256, 0, stream>>>(
            x, ei, perm, rowptr, eattr, efeat, nullptr,
            c0_ew, c0_eb, c0_w1, c0_b1, c0_w2, c0_b2, h1f);
        gine_fused_kernel<64, false><<<(NN + 3) / 4, 256, 0, stream>>>(
            h1f, ei, perm, rowptr, eattr, efeat, nullptr,
            c1_ew, c1_eb, c1_w1, c1_b1, c1_w2, c1_b2, h2f);
        h2 = h2f;
    }

    set2set_head_v3<<<BB, 1024, 0, stream>>>(h2, brow, wihT, whhT, bih, bhh,
                                             dw, dbias, ow, ob, out);
}

// Round 12
// 408.471 us; speedup vs baseline: 1.0206x; 1.0206x over previous
//
#include <hip/hip_runtime.h>
#include <math.h>

#define NN 50000
#define EE 1000000
#define BB 512

__device__ __forceinline__ float sigmoidf_(float x) { return 1.0f / (1.0f + __expf(-x)); }

// Wave-uniform loads: value lands in an SGPR; dependent FMAs use the scalar
// operand slot (no broadcast, minimal VGPR pressure).
__device__ __forceinline__ float uload(const float* p) {
    return __uint_as_float(__builtin_amdgcn_readfirstlane(__float_as_uint(*p)));
}
__device__ __forceinline__ int uloadi(const int* p) {
    return __builtin_amdgcn_readfirstlane(*p);
}

// ---------------------------------------------------------------------------
// Fused setup: zero counts + graph bounds + LSTM weight transpose.
// ---------------------------------------------------------------------------
__global__ __launch_bounds__(256) void setup_kernel(
    const int* __restrict__ batch, int* __restrict__ brow,
    const float* __restrict__ wih, const float* __restrict__ whh,
    float* __restrict__ wihT, float* __restrict__ whhT,
    int* __restrict__ counts)
{
    int i = blockIdx.x * 256 + threadIdx.x;
    if (i < NN) {
        counts[i] = 0;
        int bi = batch[i];
        int prev = (i == 0) ? -1 : batch[i - 1];
        for (int v = prev + 1; v <= bi; ++v) brow[v] = i;
        if (i == NN - 1) for (int v = bi + 1; v <= BB; ++v) brow[v] = NN;
    }
    if (i < 128 * 256) wihT[i] = wih[(i & 255) * 128 + (i >> 8)];
    if (i < 64 * 256)  whhT[i] = whh[(i & 255) * 64 + (i >> 8)];
}

// ---------------------------------------------------------------------------
// CSR build, single atomic pass: rank -> scan -> pack (atomic-free).
// ---------------------------------------------------------------------------
__global__ __launch_bounds__(256) void rank_kernel(const int* __restrict__ ei,
                                                   int* __restrict__ counts,
                                                   int* __restrict__ rnk)
{
    int e = blockIdx.x * 256 + threadIdx.x;
    if (e < EE) rnk[e] = atomicAdd(&counts[ei[EE + e]], 1);
}

__global__ __launch_bounds__(1024) void scan_kernel(const int* __restrict__ counts,
                                                    int* __restrict__ rowptr)
{
    __shared__ int s[1024];
    int t = threadIdx.x;
    const int CH = (NN + 1023) / 1024;
    int lo = t * CH, hi = lo + CH < NN ? lo + CH : NN;
    int sum = 0;
    for (int i = lo; i < hi; ++i) sum += counts[i];
    s[t] = sum;
    __syncthreads();
    for (int off = 1; off < 1024; off <<= 1) {
        int v = (t >= off) ? s[t - off] : 0;
        __syncthreads();
        s[t] += v;
        __syncthreads();
    }
    int base = (t > 0) ? s[t - 1] : 0;
    for (int i = lo; i < hi; ++i) { rowptr[i] = base; base += counts[i]; }
    if (t == 1023) rowptr[NN] = s[1023];
}

__global__ __launch_bounds__(256) void pack_kernel(
    const int* __restrict__ ei, const int* __restrict__ rnk,
    const int* __restrict__ rowptr,
    const float* __restrict__ eattr, const float* __restrict__ efeat,
    int* __restrict__ srcp, float* __restrict__ ea16)
{
    int e = blockIdx.x * 256 + threadIdx.x;
    if (e >= EE) return;
    int pos = rowptr[ei[EE + e]] + rnk[e];
    srcp[pos] = ei[e];
    const float4* pa = reinterpret_cast<const float4*>(eattr) + (size_t)e * 2;
    const float4* pf = reinterpret_cast<const float4*>(efeat) + (size_t)e * 2;
    float4* o = reinterpret_cast<float4*>(ea16 + (size_t)pos * 16);
    o[0] = pa[0]; o[1] = pa[1]; o[2] = pf[0]; o[3] = pf[1];
}

__global__ __launch_bounds__(256) void pack_ids_kernel(
    const int* __restrict__ ei, const int* __restrict__ rnk,
    const int* __restrict__ rowptr, int* __restrict__ perm)
{
    int e = blockIdx.x * 256 + threadIdx.x;
    if (e < EE) perm[rowptr[ei[EE + e]] + rnk[e]] = e;
}

// ---------------------------------------------------------------------------
// Fused GINE layer: R9-proven scalarized edge loop + one-group-ahead software
// pipeline of the pidx->x[src] gather chain (the measured latency chain).
// ---------------------------------------------------------------------------
template <int CIN, bool PACKED>
__global__ __launch_bounds__(256) void gine_fused_kernel(
    const float* __restrict__ xin, const int* __restrict__ ei,
    const int* __restrict__ pidx,   // PACKED ? srcp : perm
    const int* __restrict__ rowptr,
    const float* __restrict__ eattr, const float* __restrict__ efeat,
    const float* __restrict__ ea16,
    const float* __restrict__ ew, const float* __restrict__ eb,
    const float* __restrict__ w1, const float* __restrict__ b1,
    const float* __restrict__ w2, const float* __restrict__ b2,
    float* __restrict__ hout)
{
    __shared__ float w1_lds[CIN * 64];
    for (int i = threadIdx.x; i < CIN * 64; i += 256) w1_lds[i] = w1[i];
    __syncthreads();

    int wave = threadIdx.x >> 6, lane = threadIdx.x & 63;
    int node = blockIdx.x * 4 + wave;
    if (node >= NN) return;

    int ch = lane & (CIN - 1);

    float wreg[16];
#pragma unroll
    for (int k = 0; k < 16; ++k) wreg[k] = ew[k * CIN + ch];
    float ebv = eb[ch];

    int start = rowptr[node], end = rowptr[node + 1];
    float agg = 0.0f;

    if constexpr (PACKED) {
        if constexpr (CIN == 64) {
            int nfull = (end - start) & ~3;
            int jend4 = start + nfull;
            int j = start;
            float xc0, xc1, xc2, xc3;                 // prefetched x rows
            if (j < jend4) {                           // prologue: group 0
                int jb = __builtin_amdgcn_readfirstlane(j);
                int s0 = uloadi(pidx + jb),     s1 = uloadi(pidx + jb + 1);
                int s2 = uloadi(pidx + jb + 2), s3 = uloadi(pidx + jb + 3);
                xc0 = xin[(size_t)s0 * 64 + lane];
                xc1 = xin[(size_t)s1 * 64 + lane];
                xc2 = xin[(size_t)s2 * 64 + lane];
                xc3 = xin[(size_t)s3 * 64 + lane];
            }
            for (; j < jend4; j += 4) {
                int jb = __builtin_amdgcn_readfirstlane(j);
                bool more = (jb + 4) < jend4;          // uniform
                float xn0, xn1, xn2, xn3;
                if (more) {                            // prefetch next group
                    int s0 = uloadi(pidx + jb + 4), s1 = uloadi(pidx + jb + 5);
                    int s2 = uloadi(pidx + jb + 6), s3 = uloadi(pidx + jb + 7);
                    xn0 = xin[(size_t)s0 * 64 + lane];
                    xn1 = xin[(size_t)s1 * 64 + lane];
                    xn2 = xin[(size_t)s2 * 64 + lane];
                    xn3 = xin[(size_t)s3 * 64 + lane];
                }
                // attrs for current group: induction-addressed, scalar pipe
                float a0[16], a1[16], a2[16], a3[16];
                const float* p = ea16 + (size_t)jb * 16;
#pragma unroll
                for (int k = 0; k < 16; ++k) {
                    a0[k] = uload(p + k);
                    a1[k] = uload(p + 16 + k);
                    a2[k] = uload(p + 32 + k);
                    a3[k] = uload(p + 48 + k);
                }
                float m0 = xc0 + ebv, m1 = xc1 + ebv, m2 = xc2 + ebv, m3 = xc3 + ebv;
#pragma unroll
                for (int k = 0; k < 16; ++k) {
                    m0 += a0[k] * wreg[k];
                    m1 += a1[k] * wreg[k];
                    m2 += a2[k] * wreg[k];
                    m3 += a3[k] * wreg[k];
                }
                agg += fmaxf(m0, 0.0f) + fmaxf(m1, 0.0f)
                     + fmaxf(m2, 0.0f) + fmaxf(m3, 0.0f);
                if (more) { xc0 = xn0; xc1 = xn1; xc2 = xn2; xc3 = xn3; }
            }
            for (; j < end; ++j) {                     // tail (<=3 edges)
                int jb = __builtin_amdgcn_readfirstlane(j);
                int s0 = uloadi(pidx + jb);
                float m0 = xin[(size_t)s0 * 64 + lane] + ebv;
                const float* p = ea16 + (size_t)jb * 16;
#pragma unroll
                for (int k = 0; k < 16; ++k) m0 += uload(p + k) * wreg[k];
                agg += fmaxf(m0, 0.0f);
            }
        } else {
            // CIN == 32: one edge per half-wave, groups of 2, same pipeline.
            int half = lane >> 5;
            int nfull = (end - start) & ~1;
            int jend2 = start + nfull;
            int j = start;
            float xc;
            if (j < jend2) {
                int jb = __builtin_amdgcn_readfirstlane(j);
                int s0 = uloadi(pidx + jb), s1 = uloadi(pidx + jb + 1);
                xc = xin[(size_t)(half ? s1 : s0) * 32 + ch];
            }
            for (; j < jend2; j += 2) {
                int jb = __builtin_amdgcn_readfirstlane(j);
                bool more = (jb + 2) < jend2;
                float xn;
                if (more) {
                    int s0 = uloadi(pidx + jb + 2), s1 = uloadi(pidx + jb + 3);
                    xn = xin[(size_t)(half ? s1 : s0) * 32 + ch];
                }
                float a0[16], a1[16];
                const float* p = ea16 + (size_t)jb * 16;
#pragma unroll
                for (int k = 0; k < 16; ++k) {
                    a0[k] = uload(p + k);
                    a1[k] = uload(p + 16 + k);
                }
                float m0 = 0.0f, m1 = 0.0f;
#pragma unroll
                for (int k = 0; k < 16; ++k) {
                    m0 += a0[k] * wreg[k];
                    m1 += a1[k] * wreg[k];
                }
                agg += fmaxf(xc + (half ? m1 : m0) + ebv, 0.0f);
                if (more) xc = xn;
            }
            if (j < end) {                             // single tail edge
                int jb = __builtin_amdgcn_readfirstlane(j);
                int s0 = uloadi(pidx + jb);
                float xv = xin[(size_t)s0 * 32 + ch];
                const float* p = ea16 + (size_t)jb * 16;
                float m0 = 0.0f;
#pragma unroll
                for (int k = 0; k < 16; ++k) m0 += uload(p + k) * wreg[k];
                agg += (half == 0) ? fmaxf(xv + m0 + ebv, 0.0f) : 0.0f;
            }
            agg += __shfl_xor(agg, 32);
        }
    } else {
        // Fallback: perm indirection (R7-proven form).
        for (int j = start; j < end; ++j) {
            int jb = __builtin_amdgcn_readfirstlane(j);
            int e = uloadi(pidx + jb);
            int s0 = uloadi(ei + e);
            float xv = xin[(size_t)s0 * CIN + ch];
            const float* pa = eattr + (size_t)e * 8;
            const float* pf = efeat + (size_t)e * 8;
            float m0 = xv + ebv;
#pragma unroll
            for (int k = 0; k < 8; ++k) {
                m0 += uload(pa + k) * wreg[k];
                m0 += uload(pf + k) * wreg[8 + k];
            }
            if constexpr (CIN == 64) agg += fmaxf(m0, 0.0f);
            else                      agg += (lane < 32) ? fmaxf(m0, 0.0f) : 0.0f;
        }
        if constexpr (CIN == 32) agg += __shfl_xor(agg, 32);
    }

    // node MLP (w1 from LDS, w2 from global -- broadcast-hot)
    float h_in = 0.0f;
    if (lane < CIN) h_in = xin[(size_t)node * CIN + lane] + agg;

    float hid = b1[lane];
#pragma unroll
    for (int i = 0; i < CIN; ++i)
        hid += __shfl(h_in, i) * w1_lds[i * 64 + lane];
    hid = fmaxf(hid, 0.0f);

    float o = b2[lane];
#pragma unroll
    for (int i = 0; i < 64; ++i)
        o += __shfl(hid, i) * w2[i * 64 + lane];

    hout[(size_t)node * 64 + lane] = fmaxf(o, 0.0f);
}

// ---------------------------------------------------------------------------
// Set2Set v3: single-sweep online softmax per wave, one cross-wave combine.
// ---------------------------------------------------------------------------
__global__ __launch_bounds__(1024) void set2set_head_v3(
    const float* __restrict__ h2, const int* __restrict__ brow,
    const float* __restrict__ wihT, const float* __restrict__ whhT,
    const float* __restrict__ bih, const float* __restrict__ bhh,
    const float* __restrict__ dw, const float* __restrict__ db,
    const float* __restrict__ ow, const float* __restrict__ ob,
    float* __restrict__ outp)
{
    int b = blockIdx.x, tid = threadIdx.x;
    int wv = tid >> 6, lane = tid & 63;
    __shared__ float qstar[128], hh[64], cc[64];
    __shared__ float gpart[4][256];
    __shared__ float redw[16][64];
    __shared__ float redm[16], reds[16];

    int start = brow[b], end = brow[b + 1];

    if (tid < 128) qstar[tid] = 0.0f;
    if (tid < 64) { hh[tid] = 0.0f; cc[tid] = 0.0f; }
    __syncthreads();

    for (int step = 0; step < 3; ++step) {
        {
            int p = tid >> 8, g = tid & 255;
            float acc = 0.0f;
            const float* wT = wihT + (size_t)(32 * p) * 256 + g;
#pragma unroll 8
            for (int k = 0; k < 32; ++k) acc += qstar[32 * p + k] * wT[(size_t)k * 256];
            const float* hT = whhT + (size_t)(16 * p) * 256 + g;
#pragma unroll 8
            for (int k = 0; k < 16; ++k) acc += hh[16 * p + k] * hT[(size_t)k * 256];
            gpart[p][g] = acc;
        }
        __syncthreads();
        if (tid < 64) {
            float gi = bih[tid]       + bhh[tid]       + gpart[0][tid]       + gpart[1][tid]       + gpart[2][tid]       + gpart[3][tid];
            float gf = bih[64 + tid]  + bhh[64 + tid]  + gpart[0][64 + tid]  + gpart[1][64 + tid]  + gpart[2][64 + tid]  + gpart[3][64 + tid];
            float gg = bih[128 + tid] + bhh[128 + tid] + gpart[0][128 + tid] + gpart[1][128 + tid] + gpart[2][128 + tid] + gpart[3][128 + tid];
            float go = bih[192 + tid] + bhh[192 + tid] + gpart[0][192 + tid] + gpart[1][192 + tid] + gpart[2][192 + tid] + gpart[3][192 + tid];
            float c = sigmoidf_(gf) * cc[tid] + sigmoidf_(gi) * tanhf(gg);
            cc[tid] = c;
            hh[tid] = sigmoidf_(go) * tanhf(c);
        }
        __syncthreads();

        float qv = hh[lane];
        float mw = -INFINITY, sw = 0.0f, rw = 0.0f;
        for (int n = start + wv; n < end; n += 16) {
            float v = h2[(size_t)n * 64 + lane];
            float p = v * qv;
#pragma unroll
            for (int off = 32; off; off >>= 1) p += __shfl_xor(p, off);
            float nm = fmaxf(mw, p);
            float sc = __expf(mw - nm);
            float pe = __expf(p - nm);
            sw = sw * sc + pe;
            rw = rw * sc + pe * v;
            mw = nm;
        }
        redm[wv] = mw; reds[wv] = sw; redw[wv][lane] = rw;
        __syncthreads();
        if (tid < 64) {
            float M = -INFINITY;
#pragma unroll
            for (int w = 0; w < 16; ++w) M = fmaxf(M, redm[w]);
            float S = 0.0f, R = 0.0f;
#pragma unroll
            for (int w = 0; w < 16; ++w) {
                float mm = redm[w];
                if (mm > -INFINITY) {
                    float sc = __expf(mm - M);
                    S += reds[w] * sc;
                    R += redw[w][tid] * sc;
                }
            }
            qstar[tid] = hh[tid];
            qstar[64 + tid] = (S > 0.0f) ? R / S : 0.0f;
        }
        __syncthreads();
    }

    if (tid < 64) {
        float z = db[tid];
#pragma unroll 4
        for (int k = 0; k < 128; ++k) z += qstar[k] * dw[k * 64 + tid];
        redw[0][tid] = fmaxf(z, 0.0f);
    }
    __syncthreads();
    if (tid < 64) {
        float t = redw[0][tid] * ow[tid];
#pragma unroll
        for (int off = 32; off; off >>= 1) t += __shfl_xor(t, off);
        if (tid == 0) outp[b] = t + ob[0];
    }
}

// ---------------------------------------------------------------------------
extern "C" void kernel_launch(void* const* d_in, const int* in_sizes, int n_in,
                              void* d_out, int out_size, void* d_ws, size_t ws_size,
                              hipStream_t stream)
{
    const float* x     = (const float*)d_in[0];
    const float* eattr = (const float*)d_in[1];
    const float* efeat = (const float*)d_in[2];
    const int*   ei    = (const int*)d_in[3];
    const int*   batch = (const int*)d_in[4];
    const float* c0_ew = (const float*)d_in[5];  const float* c0_eb = (const float*)d_in[6];
    const float* c0_w1 = (const float*)d_in[7];  const float* c0_b1 = (const float*)d_in[8];
    const float* c0_w2 = (const float*)d_in[9];  const float* c0_b2 = (const float*)d_in[10];
    const float* c1_ew = (const float*)d_in[11]; const float* c1_eb = (const float*)d_in[12];
    const float* c1_w1 = (const float*)d_in[13]; const float* c1_b1 = (const float*)d_in[14];
    const float* c1_w2 = (const float*)d_in[15]; const float* c1_b2 = (const float*)d_in[16];
    const float* wih   = (const float*)d_in[17]; const float* bih   = (const float*)d_in[18];
    const float* whh   = (const float*)d_in[19]; const float* bhh   = (const float*)d_in[20];
    const float* dw    = (const float*)d_in[21]; const float* dbias = (const float*)d_in[22];
    const float* ow    = (const float*)d_in[23]; const float* ob    = (const float*)d_in[24];

    float* out = (float*)d_out;
    int* iws = (int*)d_ws;

    // layout (4B words): counts NN | rowptr NN+1 | brow BB+1 | wihT 32768 |
    //                    whhT 16384 | srcp EE | [align] ea16 16EE | h1 | h2
    // rnk (EE words) aliases h1: pack reads it before gine32 writes h1.
    int* counts = iws;
    int* rowptr = counts + NN;
    int* brow   = rowptr + NN + 1;
    size_t off0 = ((size_t)2 * NN + 1 + (BB + 1) + 15) & ~(size_t)15;
    float* wihT = (float*)(iws + off0);
    float* whhT = wihT + 128 * 256;
    int*   srcp = (int*)(whhT + 64 * 256);
    size_t offE = (off0 + 128 * 256 + 64 * 256 + EE + 15) & ~(size_t)15;
    float* ea16 = (float*)(iws + offE);
    float* h1   = ea16 + (size_t)EE * 16;
    float* h2   = h1 + (size_t)NN * 64;
    int*   rnk  = (int*)h1;
    const size_t needP = (offE + (size_t)EE * 16 + (size_t)NN * 128) * sizeof(int);

    setup_kernel<<<(NN + 255) / 256, 256, 0, stream>>>(batch, brow, wih, whh,
                                                       wihT, whhT, counts);

    if (ws_size >= needP) {
        rank_kernel<<<(EE + 255) / 256, 256, 0, stream>>>(ei, counts, rnk);
        scan_kernel<<<1, 1024, 0, stream>>>(counts, rowptr);
        pack_kernel<<<(EE + 255) / 256, 256, 0, stream>>>(
            ei, rnk, rowptr, eattr, efeat, srcp, ea16);
        gine_fused_kernel<32, true><<<(NN + 3) / 4, 256, 0, stream>>>(
            x, ei, srcp, rowptr, eattr, efeat, ea16,
            c0_ew, c0_eb, c0_w1, c0_b1, c0_w2, c0_b2, h1);
        gine_fused_kernel<64, true><<<(NN + 3) / 4, 256, 0, stream>>>(
            h1, ei, srcp, rowptr, eattr, efeat, ea16,
            c1_ew, c1_eb, c1_w1, c1_b1, c1_w2, c1_b2, h2);
    } else {
        int* perm = srcp;
        float* h1f = (float*)(iws + offE);
        float* h2f = h1f + (size_t)NN * 64;
        int* rnkf  = (int*)(h2f + (size_t)NN * 64);
        rank_kernel<<<(EE + 255) / 256, 256, 0, stream>>>(ei, counts, rnkf);
        scan_kernel<<<1, 1024, 0, stream>>>(counts, rowptr);
        pack_ids_kernel<<<(EE + 255) / 256, 256, 0, stream>>>(ei, rnkf, rowptr, perm);
        gine_fused_kernel<32, false><<<(NN + 3) / 4, 256, 0, stream>>>(
            x, ei, perm, rowptr, eattr, efeat, nullptr,
            c0_ew, c0_eb, c0_w1, c0_b1, c0_w2, c0_b2, h1f);
        gine_fused_kernel<64, false><<<(NN + 3) / 4, 256, 0, stream>>>(
            h1f, ei, perm, rowptr, eattr, efeat, nullptr,
            c1_ew, c1_eb, c1_w1, c1_b1, c1_w2, c1_b2, h2f);
        h2 = h2f;
    }

    set2set_head_v3<<<BB, 1024, 0, stream>>>(h2, brow, wihT, whhT, bih, bhh,
                                             dw, dbias, ow, ob, out);
}

// Round 13
// 386.832 us; speedup vs baseline: 1.0777x; 1.0559x over previous
//
#include <hip/hip_runtime.h>
#include <math.h>

#define NN 50000
#define EE 1000000
#define BB 512

typedef _Float16 hf;
typedef __attribute__((ext_vector_type(2))) _Float16 hf2;

__device__ __forceinline__ float sigmoidf_(float x) { return 1.0f / (1.0f + __expf(-x)); }

__device__ __forceinline__ int uloadi(const int* p) {
    return __builtin_amdgcn_readfirstlane(*p);
}
__device__ __forceinline__ unsigned uloadu(const unsigned* p) {
    return (unsigned)__builtin_amdgcn_readfirstlane((int)*p);
}

// f32 pair -> packed half2 (as uint)
__device__ __forceinline__ unsigned pack2(float a, float b) {
    hf2 h; h.x = (_Float16)a; h.y = (_Float16)b;
    return __builtin_bit_cast(unsigned, h);
}

// acc += a(2xf16) . w(2xf16), f32 accumulate (V_DOT2_F32_F16 when available)
__device__ __forceinline__ float dot2acc(unsigned au, hf2 w, float acc) {
    hf2 a = __builtin_bit_cast(hf2, au);
#if __has_builtin(__builtin_amdgcn_fdot2)
    return __builtin_amdgcn_fdot2(a, w, acc, false);
#else
    return acc + (float)a.x * (float)w.x + (float)a.y * (float)w.y;
#endif
}

// ---------------------------------------------------------------------------
// Fused setup: zero counts + graph bounds + LSTM transpose + x -> fp16.
// ---------------------------------------------------------------------------
__global__ __launch_bounds__(256) void setup_kernel(
    const int* __restrict__ batch, int* __restrict__ brow,
    const float* __restrict__ wih, const float* __restrict__ whh,
    float* __restrict__ wihT, float* __restrict__ whhT,
    int* __restrict__ counts, const float* __restrict__ x, unsigned* __restrict__ xh)
{
    int i = blockIdx.x * 256 + threadIdx.x;
    if (i < NN) {
        counts[i] = 0;
        int bi = batch[i];
        int prev = (i == 0) ? -1 : batch[i - 1];
        for (int v = prev + 1; v <= bi; ++v) brow[v] = i;
        if (i == NN - 1) for (int v = bi + 1; v <= BB; ++v) brow[v] = NN;
    }
    if (i < 128 * 256) wihT[i] = wih[(i & 255) * 128 + (i >> 8)];
    if (i < 64 * 256)  whhT[i] = whh[(i & 255) * 64 + (i >> 8)];
    if (i < NN * 8) {   // 4 floats -> 2 uints per thread
        float4 v = reinterpret_cast<const float4*>(x)[i];
        uint2 o; o.x = pack2(v.x, v.y); o.y = pack2(v.z, v.w);
        reinterpret_cast<uint2*>(xh)[i] = o;
    }
}

// ---------------------------------------------------------------------------
// CSR build, single atomic pass: rank -> scan -> pack (atomic-free).
// ---------------------------------------------------------------------------
__global__ __launch_bounds__(256) void rank_kernel(const int* __restrict__ ei,
                                                   int* __restrict__ counts,
                                                   int* __restrict__ rnk)
{
    int e = blockIdx.x * 256 + threadIdx.x;
    if (e < EE) rnk[e] = atomicAdd(&counts[ei[EE + e]], 1);
}

__global__ __launch_bounds__(1024) void scan_kernel(const int* __restrict__ counts,
                                                    int* __restrict__ rowptr)
{
    __shared__ int s[1024];
    int t = threadIdx.x;
    const int CH = (NN + 1023) / 1024;
    int lo = t * CH, hi = lo + CH < NN ? lo + CH : NN;
    int sum = 0;
    for (int i = lo; i < hi; ++i) sum += counts[i];
    s[t] = sum;
    __syncthreads();
    for (int off = 1; off < 1024; off <<= 1) {
        int v = (t >= off) ? s[t - off] : 0;
        __syncthreads();
        s[t] += v;
        __syncthreads();
    }
    int base = (t > 0) ? s[t - 1] : 0;
    for (int i = lo; i < hi; ++i) { rowptr[i] = base; base += counts[i]; }
    if (t == 1023) rowptr[NN] = s[1023];
}

// pack: coalesced attr reads, f32->f16 convert, 32B scattered writes + srcp.
__global__ __launch_bounds__(256) void pack_kernel(
    const int* __restrict__ ei, const int* __restrict__ rnk,
    const int* __restrict__ rowptr,
    const float* __restrict__ eattr, const float* __restrict__ efeat,
    int* __restrict__ srcp, unsigned* __restrict__ eah)
{
    int e = blockIdx.x * 256 + threadIdx.x;
    if (e >= EE) return;
    int pos = rowptr[ei[EE + e]] + rnk[e];
    srcp[pos] = ei[e];
    const float4* pa = reinterpret_cast<const float4*>(eattr) + (size_t)e * 2;
    const float4* pf = reinterpret_cast<const float4*>(efeat) + (size_t)e * 2;
    float4 v0 = pa[0], v1 = pa[1], v2 = pf[0], v3 = pf[1];
    uint4 o0, o1;
    o0.x = pack2(v0.x, v0.y); o0.y = pack2(v0.z, v0.w);
    o0.z = pack2(v1.x, v1.y); o0.w = pack2(v1.z, v1.w);
    o1.x = pack2(v2.x, v2.y); o1.y = pack2(v2.z, v2.w);
    o1.z = pack2(v3.x, v3.y); o1.w = pack2(v3.z, v3.w);
    uint4* o = reinterpret_cast<uint4*>(eah + (size_t)pos * 8);
    o[0] = o0; o[1] = o1;
}

// ---------------------------------------------------------------------------
// Fused GINE layer, fp16 storage: scalarized attrs (8 uints/edge in SGPRs),
// fp16 x-gather (128B/row), dot2 f32-accum math. One wave per node.
// ---------------------------------------------------------------------------
template <int CIN>
__global__ __launch_bounds__(256) void gine_fused_kernel(
    const hf* __restrict__ xin, const int* __restrict__ pidx,
    const int* __restrict__ rowptr, const unsigned* __restrict__ eah,
    const float* __restrict__ ew, const float* __restrict__ eb,
    const float* __restrict__ w1, const float* __restrict__ b1,
    const float* __restrict__ w2, const float* __restrict__ b2,
    hf* __restrict__ hout)
{
    __shared__ float w1_lds[CIN * 64];
    for (int i = threadIdx.x; i < CIN * 64; i += 256) w1_lds[i] = w1[i];
    __syncthreads();

    int wave = threadIdx.x >> 6, lane = threadIdx.x & 63;
    int node = blockIdx.x * 4 + wave;
    if (node >= NN) return;

    int ch = lane & (CIN - 1);

    hf2 wh[8];
#pragma unroll
    for (int k = 0; k < 8; ++k) {
        wh[k].x = (_Float16)ew[(2 * k) * CIN + ch];
        wh[k].y = (_Float16)ew[(2 * k + 1) * CIN + ch];
    }
    float ebv = eb[ch];

    int start = rowptr[node], end = rowptr[node + 1];
    float agg = 0.0f;

    if constexpr (CIN == 64) {
        int j = start;
        for (; j + 3 < end; j += 4) {
            int jb = __builtin_amdgcn_readfirstlane(j);
            int s0 = uloadi(pidx + jb),     s1 = uloadi(pidx + jb + 1);
            int s2 = uloadi(pidx + jb + 2), s3 = uloadi(pidx + jb + 3);
            float m0 = (float)xin[(size_t)s0 * 64 + lane] + ebv;
            float m1 = (float)xin[(size_t)s1 * 64 + lane] + ebv;
            float m2 = (float)xin[(size_t)s2 * 64 + lane] + ebv;
            float m3 = (float)xin[(size_t)s3 * 64 + lane] + ebv;
            const unsigned* p = eah + (size_t)jb * 8;
            unsigned a0[8], a1[8], a2[8], a3[8];
#pragma unroll
            for (int k = 0; k < 8; ++k) {
                a0[k] = uloadu(p + k);
                a1[k] = uloadu(p + 8 + k);
                a2[k] = uloadu(p + 16 + k);
                a3[k] = uloadu(p + 24 + k);
            }
#pragma unroll
            for (int k = 0; k < 8; ++k) {
                m0 = dot2acc(a0[k], wh[k], m0);
                m1 = dot2acc(a1[k], wh[k], m1);
                m2 = dot2acc(a2[k], wh[k], m2);
                m3 = dot2acc(a3[k], wh[k], m3);
            }
            agg += fmaxf(m0, 0.0f) + fmaxf(m1, 0.0f)
                 + fmaxf(m2, 0.0f) + fmaxf(m3, 0.0f);
        }
        for (; j < end; ++j) {
            int jb = __builtin_amdgcn_readfirstlane(j);
            int s0 = uloadi(pidx + jb);
            float m0 = (float)xin[(size_t)s0 * 64 + lane] + ebv;
            const unsigned* p = eah + (size_t)jb * 8;
#pragma unroll
            for (int k = 0; k < 8; ++k) m0 = dot2acc(uloadu(p + k), wh[k], m0);
            agg += fmaxf(m0, 0.0f);
        }
    } else {
        // CIN == 32: one edge per half-wave; both sums from SGPR operands.
        int half = lane >> 5;
        int j = start;
        for (; j + 1 < end; j += 2) {
            int jb = __builtin_amdgcn_readfirstlane(j);
            int s0 = uloadi(pidx + jb);
            int s1 = uloadi(pidx + jb + 1);
            float xv = (float)xin[(size_t)(half ? s1 : s0) * 32 + ch];
            const unsigned* p = eah + (size_t)jb * 8;
            unsigned a0[8], a1[8];
#pragma unroll
            for (int k = 0; k < 8; ++k) { a0[k] = uloadu(p + k); a1[k] = uloadu(p + 8 + k); }
            float m0 = 0.0f, m1 = 0.0f;
#pragma unroll
            for (int k = 0; k < 8; ++k) {
                m0 = dot2acc(a0[k], wh[k], m0);
                m1 = dot2acc(a1[k], wh[k], m1);
            }
            agg += fmaxf(xv + (half ? m1 : m0) + ebv, 0.0f);
        }
        if (j < end) {  // single tail edge: only half 0 contributes
            int jb = __builtin_amdgcn_readfirstlane(j);
            int s0 = uloadi(pidx + jb);
            float xv = (float)xin[(size_t)s0 * 32 + ch];
            const unsigned* p = eah + (size_t)jb * 8;
            float m0 = 0.0f;
#pragma unroll
            for (int k = 0; k < 8; ++k) m0 = dot2acc(uloadu(p + k), wh[k], m0);
            agg += (half == 0) ? fmaxf(xv + m0 + ebv, 0.0f) : 0.0f;
        }
        agg += __shfl_xor(agg, 32);
    }

    // node MLP (w1 from LDS, w2 from global -- broadcast-hot)
    float h_in = 0.0f;
    if (lane < CIN) h_in = (float)xin[(size_t)node * CIN + lane] + agg;

    float hid = b1[lane];
#pragma unroll
    for (int i = 0; i < CIN; ++i)
        hid += __shfl(h_in, i) * w1_lds[i * 64 + lane];
    hid = fmaxf(hid, 0.0f);

    float o = b2[lane];
#pragma unroll
    for (int i = 0; i < 64; ++i)
        o += __shfl(hid, i) * w2[i * 64 + lane];

    hout[(size_t)node * 64 + lane] = (hf)fmaxf(o, 0.0f);
}

// ---------------------------------------------------------------------------
// Set2Set v3 (fp16 h2): single-sweep online softmax per wave.
// ---------------------------------------------------------------------------
__global__ __launch_bounds__(1024) void set2set_head_v3(
    const hf* __restrict__ h2, const int* __restrict__ brow,
    const float* __restrict__ wihT, const float* __restrict__ whhT,
    const float* __restrict__ bih, const float* __restrict__ bhh,
    const float* __restrict__ dw, const float* __restrict__ db,
    const float* __restrict__ ow, const float* __restrict__ ob,
    float* __restrict__ outp)
{
    int b = blockIdx.x, tid = threadIdx.x;
    int wv = tid >> 6, lane = tid & 63;
    __shared__ float qstar[128], hh[64], cc[64];
    __shared__ float gpart[4][256];
    __shared__ float redw[16][64];
    __shared__ float redm[16], reds[16];

    int start = brow[b], end = brow[b + 1];

    if (tid < 128) qstar[tid] = 0.0f;
    if (tid < 64) { hh[tid] = 0.0f; cc[tid] = 0.0f; }
    __syncthreads();

    for (int step = 0; step < 3; ++step) {
        {
            int p = tid >> 8, g = tid & 255;
            float acc = 0.0f;
            const float* wT = wihT + (size_t)(32 * p) * 256 + g;
#pragma unroll 8
            for (int k = 0; k < 32; ++k) acc += qstar[32 * p + k] * wT[(size_t)k * 256];
            const float* hT = whhT + (size_t)(16 * p) * 256 + g;
#pragma unroll 8
            for (int k = 0; k < 16; ++k) acc += hh[16 * p + k] * hT[(size_t)k * 256];
            gpart[p][g] = acc;
        }
        __syncthreads();
        if (tid < 64) {
            float gi = bih[tid]       + bhh[tid]       + gpart[0][tid]       + gpart[1][tid]       + gpart[2][tid]       + gpart[3][tid];
            float gf = bih[64 + tid]  + bhh[64 + tid]  + gpart[0][64 + tid]  + gpart[1][64 + tid]  + gpart[2][64 + tid]  + gpart[3][64 + tid];
            float gg = bih[128 + tid] + bhh[128 + tid] + gpart[0][128 + tid] + gpart[1][128 + tid] + gpart[2][128 + tid] + gpart[3][128 + tid];
            float go = bih[192 + tid] + bhh[192 + tid] + gpart[0][192 + tid] + gpart[1][192 + tid] + gpart[2][192 + tid] + gpart[3][192 + tid];
            float c = sigmoidf_(gf) * cc[tid] + sigmoidf_(gi) * tanhf(gg);
            cc[tid] = c;
            hh[tid] = sigmoidf_(go) * tanhf(c);
        }
        __syncthreads();

        float qv = hh[lane];
        float mw = -INFINITY, sw = 0.0f, rw = 0.0f;
        for (int n = start + wv; n < end; n += 16) {
            float v = (float)h2[(size_t)n * 64 + lane];
            float p = v * qv;
#pragma unroll
            for (int off = 32; off; off >>= 1) p += __shfl_xor(p, off);
            float nm = fmaxf(mw, p);
            float sc = __expf(mw - nm);
            float pe = __expf(p - nm);
            sw = sw * sc + pe;
            rw = rw * sc + pe * v;
            mw = nm;
        }
        redm[wv] = mw; reds[wv] = sw; redw[wv][lane] = rw;
        __syncthreads();
        if (tid < 64) {
            float M = -INFINITY;
#pragma unroll
            for (int w = 0; w < 16; ++w) M = fmaxf(M, redm[w]);
            float S = 0.0f, R = 0.0f;
#pragma unroll
            for (int w = 0; w < 16; ++w) {
                float mm = redm[w];
                if (mm > -INFINITY) {
                    float sc = __expf(mm - M);
                    S += reds[w] * sc;
                    R += redw[w][tid] * sc;
                }
            }
            qstar[tid] = hh[tid];
            qstar[64 + tid] = (S > 0.0f) ? R / S : 0.0f;
        }
        __syncthreads();
    }

    if (tid < 64) {
        float z = db[tid];
#pragma unroll 4
        for (int k = 0; k < 128; ++k) z += qstar[k] * dw[k * 64 + tid];
        redw[0][tid] = fmaxf(z, 0.0f);
    }
    __syncthreads();
    if (tid < 64) {
        float t = redw[0][tid] * ow[tid];
#pragma unroll
        for (int off = 32; off; off >>= 1) t += __shfl_xor(t, off);
        if (tid == 0) outp[b] = t + ob[0];
    }
}

// ---------------------------------------------------------------------------
extern "C" void kernel_launch(void* const* d_in, const int* in_sizes, int n_in,
                              void* d_out, int out_size, void* d_ws, size_t ws_size,
                              hipStream_t stream)
{
    const float* x     = (const float*)d_in[0];
    const float* eattr = (const float*)d_in[1];
    const float* efeat = (const float*)d_in[2];
    const int*   ei    = (const int*)d_in[3];
    const int*   batch = (const int*)d_in[4];
    const float* c0_ew = (const float*)d_in[5];  const float* c0_eb = (const float*)d_in[6];
    const float* c0_w1 = (const float*)d_in[7];  const float* c0_b1 = (const float*)d_in[8];
    const float* c0_w2 = (const float*)d_in[9];  const float* c0_b2 = (const float*)d_in[10];
    const float* c1_ew = (const float*)d_in[11]; const float* c1_eb = (const float*)d_in[12];
    const float* c1_w1 = (const float*)d_in[13]; const float* c1_b1 = (const float*)d_in[14];
    const float* c1_w2 = (const float*)d_in[15]; const float* c1_b2 = (const float*)d_in[16];
    const float* wih   = (const float*)d_in[17]; const float* bih   = (const float*)d_in[18];
    const float* whh   = (const float*)d_in[19]; const float* bhh   = (const float*)d_in[20];
    const float* dw    = (const float*)d_in[21]; const float* dbias = (const float*)d_in[22];
    const float* ow    = (const float*)d_in[23]; const float* ob    = (const float*)d_in[24];

    float* out = (float*)d_out;
    int* iws = (int*)d_ws;

    // layout (4B words): counts NN | rowptr NN+1 | brow BB+1 | wihT 32768 |
    //   whhT 16384 | srcp EE | xh NN*16 | [align] eah EE*8 | h1h NN*32 |
    //   h2h NN*32.  rnk (EE words) aliases h1h (pack reads rnk before gine32
    //   writes h1h; kernels are stream-serialized).
    int* counts = iws;
    int* rowptr = counts + NN;
    int* brow   = rowptr + NN + 1;
    size_t off0 = ((size_t)2 * NN + 1 + (BB + 1) + 15) & ~(size_t)15;
    float* wihT = (float*)(iws + off0);
    float* whhT = wihT + 128 * 256;
    int*   srcp = (int*)(whhT + 64 * 256);
    unsigned* xh = (unsigned*)(srcp + EE);
    size_t offE = (off0 + 128 * 256 + 64 * 256 + EE + (size_t)NN * 16 + 15) & ~(size_t)15;
    unsigned* eah = (unsigned*)(iws + offE);
    hf* h1h = (hf*)(eah + (size_t)EE * 8);
    hf* h2h = h1h + (size_t)NN * 64;
    int* rnk = (int*)h1h;

    int setup_grid = (NN * 8 + 255) / 256;   // covers x-convert (largest clause)
    setup_kernel<<<setup_grid, 256, 0, stream>>>(batch, brow, wih, whh,
                                                 wihT, whhT, counts, x, xh);
    rank_kernel<<<(EE + 255) / 256, 256, 0, stream>>>(ei, counts, rnk);
    scan_kernel<<<1, 1024, 0, stream>>>(counts, rowptr);
    pack_kernel<<<(EE + 255) / 256, 256, 0, stream>>>(
        ei, rnk, rowptr, eattr, efeat, srcp, eah);
    gine_fused_kernel<32><<<(NN + 3) / 4, 256, 0, stream>>>(
        (const hf*)xh, srcp, rowptr, eah,
        c0_ew, c0_eb, c0_w1, c0_b1, c0_w2, c0_b2, h1h);
    gine_fused_kernel<64><<<(NN + 3) / 4, 256, 0, stream>>>(
        h1h, srcp, rowptr, eah,
        c1_ew, c1_eb, c1_w1, c1_b1, c1_w2, c1_b2, h2h);
    set2set_head_v3<<<BB, 1024, 0, stream>>>(h2h, brow, wihT, whhT, bih, bhh,
                                             dw, dbias, ow, ob, out);
}